// Round 1
// baseline (1558.226 us; speedup 1.0000x reference)
//
#include <hip/hip_runtime.h>
#include <hip/hip_bf16.h>
#include <math.h>

#define E_NUM 800000
#define NN 50000
#define NG 50
#define TILE_E 64
#define N_TILES (E_NUM / TILE_E)
#define EDGE_GRID 512

typedef __bf16 bf16x8 __attribute__((ext_vector_type(8)));
typedef float f32x4 __attribute__((ext_vector_type(4)));

__device__ __forceinline__ unsigned short f2b(float f) {
  union { float f; unsigned u; } v; v.f = f;
  unsigned u = v.u;
  u += 0x7fffu + ((u >> 16) & 1u);
  return (unsigned short)(u >> 16);
}

__device__ __forceinline__ float sspf(float v) {
  // softplus(v) - log(2), numerically stable
  return fmaxf(v, 0.f) + log1pf(expf(-fabsf(v))) - 0.69314718055994531f;
}

// out[n][f] = (opt act)(X[n] . Wm[f] + bias[f]); Wm is [128][128] row-major.
__global__ __launch_bounds__(256) void k_nodegemm(
    const float* __restrict__ X, const float* __restrict__ Wm,
    const float* __restrict__ bias, float* __restrict__ out, int act)
{
  const int f  = threadIdx.x & 127;
  const int nb = (blockIdx.x * 2 + (threadIdx.x >> 7)) * 4;
  const float4* __restrict__ wp = (const float4*)(Wm + f * 128);
  const float4* __restrict__ x0 = (const float4*)(X + (long)(nb + 0) * 128);
  const float4* __restrict__ x1 = (const float4*)(X + (long)(nb + 1) * 128);
  const float4* __restrict__ x2 = (const float4*)(X + (long)(nb + 2) * 128);
  const float4* __restrict__ x3 = (const float4*)(X + (long)(nb + 3) * 128);
  float a0 = 0.f, a1 = 0.f, a2 = 0.f, a3 = 0.f;
#pragma unroll 8
  for (int kk = 0; kk < 32; ++kk) {
    float4 wv = wp[kk];
    float4 v0 = x0[kk]; a0 += wv.x*v0.x + wv.y*v0.y + wv.z*v0.z + wv.w*v0.w;
    float4 v1 = x1[kk]; a1 += wv.x*v1.x + wv.y*v1.y + wv.z*v1.z + wv.w*v1.w;
    float4 v2 = x2[kk]; a2 += wv.x*v2.x + wv.y*v2.y + wv.z*v2.z + wv.w*v2.w;
    float4 v3 = x3[kk]; a3 += wv.x*v3.x + wv.y*v3.y + wv.z*v3.z + wv.w*v3.w;
  }
  float b = bias ? bias[f] : 0.f;
  a0 += b; a1 += b; a2 += b; a3 += b;
  if (act) { a0 = sspf(a0); a1 = sspf(a1); a2 = sspf(a2); a3 = sspf(a3); }
  out[(long)(nb + 0) * 128 + f] = a0;
  out[(long)(nb + 1) * 128 + f] = a1;
  out[(long)(nb + 2) * 128 + f] = a2;
  out[(long)(nb + 3) * 128 + f] = a3;
}

// Edge kernel: per 64-edge tile, bf16 MFMA 2-layer MLP, cutoff scale,
// gather h[src], atomic scatter-add into agg[dst].
__global__ __launch_bounds__(256) void k_edge(
    const float* __restrict__ attr,   // [E][50]
    const int*   __restrict__ ei,     // [2][E]
    const float* __restrict__ ew,     // [E]
    const float* __restrict__ w1,     // [128][50]
    const float* __restrict__ b1,     // [128]
    const float* __restrict__ w2,     // [128][128]
    const float* __restrict__ b2,     // [128]
    const float* __restrict__ h,      // [NN][128]
    float*       __restrict__ agg)    // [NN][128]
{
  // exactly 64 KB static LDS; s_he doubles as the attr staging region
  __shared__ __attribute__((aligned(16))) unsigned short s_he[64 * 128];
  __shared__ __attribute__((aligned(16))) unsigned short s_w1[128 * 64];
  __shared__ __attribute__((aligned(16))) unsigned short s_w2[128 * 128];

  const int tid  = threadIdx.x;
  const int w    = tid >> 6;
  const int lane = tid & 63;
  const int q    = lane >> 4;
  const int n16  = lane & 15;

  // stage weights once (bf16, XOR-chunk swizzle, K zero-padded 50->64)
  for (int i = tid; i < 128 * 64; i += 256) {
    int f = i >> 6, k = i & 63;
    float v = (k < NG) ? w1[f * NG + k] : 0.f;
    int pos = (f << 6) + ((((k >> 3) ^ (f & 7)) << 3)) + (k & 7);
    s_w1[pos] = f2b(v);
  }
  for (int i = tid; i < 128 * 128; i += 256) {
    int f = i >> 7, k = i & 127;
    int pos = (f << 7) + ((((k >> 3) ^ (f & 15)) << 3)) + (k & 7);
    s_w2[pos] = f2b(w2[i]);
  }
  float b1v[8], b2v[8];
#pragma unroll
  for (int t = 0; t < 8; ++t) {
    b1v[t] = b1[t * 16 + n16];
    b2v[t] = b2[t * 16 + n16];
  }

  const int eloc = w * 16 + n16;  // this wave's A-operand row (local edge)

  for (int tile = blockIdx.x; tile < N_TILES; tile += gridDim.x) {
    const int e0 = tile * TILE_E;
    __syncthreads();  // prior tile done with s_he region
    // stage attr tile into s_he region (bf16, zero-pad K to 64, swizzled)
    for (int i = tid; i < 64 * 64; i += 256) {
      int e = i >> 6, k = i & 63;
      float v = (k < NG) ? attr[(e0 + e) * NG + k] : 0.f;
      int pos = (e << 6) + ((((k >> 3) ^ (e & 7)) << 3)) + (k & 7);
      s_he[pos] = f2b(v);
    }
    __syncthreads();
    // preload layer-1 A fragments (per-lane row = eloc)
    bf16x8 a0 = *(const bf16x8*)&s_he[(eloc << 6) + (((q    ) ^ (eloc & 7)) << 3)];
    bf16x8 a1 = *(const bf16x8*)&s_he[(eloc << 6) + (((4 + q) ^ (eloc & 7)) << 3)];
    __syncthreads();  // everyone has attr in regs; region reusable as h_e

    // layer 1: h_e = ssp(attr @ w1^T + b1), write h_e to LDS in [e][k] layout
#pragma unroll
    for (int t = 0; t < 8; ++t) {
      int f = t * 16 + n16;
      bf16x8 bA = *(const bf16x8*)&s_w1[(f << 6) + (((q    ) ^ (f & 7)) << 3)];
      bf16x8 bB = *(const bf16x8*)&s_w1[(f << 6) + (((4 + q) ^ (f & 7)) << 3)];
      f32x4 acc = {0.f, 0.f, 0.f, 0.f};
      acc = __builtin_amdgcn_mfma_f32_16x16x32_bf16(a0, bA, acc, 0, 0, 0);
      acc = __builtin_amdgcn_mfma_f32_16x16x32_bf16(a1, bB, acc, 0, 0, 0);
      int kf = t * 16 + n16;
#pragma unroll
      for (int r = 0; r < 4; ++r) {
        int e = w * 16 + q * 4 + r;   // C-layout row
        float hv = sspf(acc[r] + b1v[t]);
        int pos = (e << 7) + ((((kf >> 3) ^ (e & 15)) << 3)) + (kf & 7);
        s_he[pos] = f2b(hv);
      }
    }
    __syncthreads();

    // layer-2 A fragments (own wave's h_e rows)
    bf16x8 a2[4];
#pragma unroll
    for (int ks = 0; ks < 4; ++ks)
      a2[ks] = *(const bf16x8*)&s_he[(eloc << 7) + ((((ks * 4 + q)) ^ (eloc & 15)) << 3)];

    // per-edge epilogue metadata
    int src[4], dst[4]; float cv[4];
#pragma unroll
    for (int r = 0; r < 4; ++r) {
      int e = e0 + w * 16 + q * 4 + r;
      src[r] = ei[e];
      dst[r] = ei[E_NUM + e];
      cv[r] = 0.5f * (cosf(ew[e] * 0.31415926535897932f) + 1.f);
    }

    // layer 2 + epilogue: W = (h_e @ w2^T + b2)*C; msg = h[src]*W; agg[dst] += msg
#pragma unroll
    for (int t = 0; t < 8; ++t) {
      int f = t * 16 + n16;
      f32x4 acc = {0.f, 0.f, 0.f, 0.f};
#pragma unroll
      for (int ks = 0; ks < 4; ++ks) {
        bf16x8 bb = *(const bf16x8*)&s_w2[(f << 7) + ((((ks * 4 + q)) ^ (f & 15)) << 3)];
        acc = __builtin_amdgcn_mfma_f32_16x16x32_bf16(a2[ks], bb, acc, 0, 0, 0);
      }
#pragma unroll
      for (int r = 0; r < 4; ++r) {
        float Wv = (acc[r] + b2v[t]) * cv[r];
        float msg = h[src[r] * 128 + f] * Wv;
        atomicAdd(&agg[dst[r] * 128 + f], msg);
      }
    }
  }
}

extern "C" void kernel_launch(void* const* d_in, const int* in_sizes, int n_in,
                              void* d_out, int out_size, void* d_ws, size_t ws_size,
                              hipStream_t stream) {
  const float* x     = (const float*)d_in[0];
  const int*   ei    = (const int*)  d_in[1];
  const float* ew    = (const float*)d_in[2];
  const float* attr  = (const float*)d_in[3];
  const float* w1    = (const float*)d_in[4];
  const float* b1    = (const float*)d_in[5];
  const float* w2    = (const float*)d_in[6];
  const float* b2    = (const float*)d_in[7];
  const float* lin1w = (const float*)d_in[8];
  const float* lin2w = (const float*)d_in[9];
  const float* lin2b = (const float*)d_in[10];
  const float* linw  = (const float*)d_in[11];
  const float* linb  = (const float*)d_in[12];
  float* out = (float*)d_out;

  float* agg = (float*)d_ws;                       // [NN][128] fp32
  float* h   = agg + (size_t)NN * 128;             // [NN][128] fp32 (reused as h2)

  hipMemsetAsync(agg, 0, (size_t)NN * 128 * sizeof(float), stream);
  k_nodegemm<<<NN / 8, 256, 0, stream>>>(x, lin1w, nullptr, h, 0);
  k_edge<<<EDGE_GRID, 256, 0, stream>>>(attr, ei, ew, w1, b1, w2, b2, h, agg);
  k_nodegemm<<<NN / 8, 256, 0, stream>>>(agg, lin2w, lin2b, h, 1);  // h2 (overwrites h)
  k_nodegemm<<<NN / 8, 256, 0, stream>>>(h, linw, linb, out, 0);
}

// Round 3
// 889.699 us; speedup vs baseline: 1.7514x; 1.7514x over previous
//
#include <hip/hip_runtime.h>
#include <hip/hip_bf16.h>
#include <math.h>

#define E_NUM 800000
#define NN 50000
#define NG 50
#define TILE_E 128
#define N_TILES (E_NUM / TILE_E)
#define EDGE_GRID 512

typedef __bf16 bf16x8 __attribute__((ext_vector_type(8)));
typedef float f32x4 __attribute__((ext_vector_type(4)));
typedef unsigned short ushortx8 __attribute__((ext_vector_type(8)));

__device__ __forceinline__ unsigned short f2b(float f) {
  union { float f; unsigned u; } v; v.f = f;
  unsigned u = v.u;
  u += 0x7fffu + ((u >> 16) & 1u);
  return (unsigned short)(u >> 16);
}

// shifted softplus via hw exp2/log2: max(x,0) + ln2*log2(0.5 + 0.5*2^(-|x|*log2e))
__device__ __forceinline__ float sspf(float v) {
  float e = __builtin_amdgcn_exp2f(-1.4426950408889634f * fabsf(v));
  return fmaxf(v, 0.f) + 0.6931471805599453f * __builtin_amdgcn_logf(fmaf(0.5f, e, 0.5f));
}

// out[n][f] = (opt ssp)(X[n] . Wm[f] + bias[f]); bf16 MFMA, 128-node blocks.
__global__ __launch_bounds__(256) void k_mfma_gemm(
    const float* __restrict__ X, const float* __restrict__ Wm,
    const float* __restrict__ bias, float* __restrict__ out, int act, int nrows)
{
  __shared__ __attribute__((aligned(16))) unsigned short s_x[128 * 128];
  __shared__ __attribute__((aligned(16))) unsigned short s_w[128 * 128];
  const int tid = threadIdx.x;
  const int w = tid >> 6, lane = tid & 63, q = lane >> 4, n16 = lane & 15;
  const int base = blockIdx.x * 128;

  // stage W [128][128] -> bf16 swizzled
  for (int c = tid; c < 128 * 16; c += 256) {
    int f = c >> 4, ch = c & 15;
    const float4* wp = (const float4*)(Wm + f * 128 + ch * 8);
    float4 v0 = wp[0], v1 = wp[1];
    ushortx8 v = { f2b(v0.x), f2b(v0.y), f2b(v0.z), f2b(v0.w),
                   f2b(v1.x), f2b(v1.y), f2b(v1.z), f2b(v1.w) };
    *(ushortx8*)&s_w[(f << 7) + ((ch ^ (f & 15)) << 3)] = v;
  }
  // stage X tile (guarded rows)
  for (int c = tid; c < 128 * 16; c += 256) {
    int r = c >> 4, ch = c & 15;
    int n = base + r;
    float4 v0 = {0.f, 0.f, 0.f, 0.f}, v1 = v0;
    if (n < nrows) {
      const float4* xp = (const float4*)(X + (long)n * 128 + ch * 8);
      v0 = xp[0]; v1 = xp[1];
    }
    ushortx8 v = { f2b(v0.x), f2b(v0.y), f2b(v0.z), f2b(v0.w),
                   f2b(v1.x), f2b(v1.y), f2b(v1.z), f2b(v1.w) };
    *(ushortx8*)&s_x[(r << 7) + ((ch ^ (r & 15)) << 3)] = v;
  }
  __syncthreads();

  float bv[8];
#pragma unroll
  for (int t = 0; t < 8; ++t) bv[t] = bias ? bias[t * 16 + n16] : 0.f;

  bf16x8 a[2][4];
#pragma unroll
  for (int g = 0; g < 2; ++g) {
    int r = w * 32 + g * 16 + n16;
#pragma unroll
    for (int ks = 0; ks < 4; ++ks)
      a[g][ks] = *(const bf16x8*)&s_x[(r << 7) + (((ks * 4 + q) ^ (r & 15)) << 3)];
  }
#pragma unroll
  for (int t = 0; t < 8; ++t) {
    int f = t * 16 + n16;
    bf16x8 b[4];
#pragma unroll
    for (int ks = 0; ks < 4; ++ks)
      b[ks] = *(const bf16x8*)&s_w[(f << 7) + (((ks * 4 + q) ^ (f & 15)) << 3)];
#pragma unroll
    for (int g = 0; g < 2; ++g) {
      f32x4 acc = {0.f, 0.f, 0.f, 0.f};
#pragma unroll
      for (int ks = 0; ks < 4; ++ks)
        acc = __builtin_amdgcn_mfma_f32_16x16x32_bf16(a[g][ks], b[ks], acc, 0, 0, 0);
#pragma unroll
      for (int r = 0; r < 4; ++r) {
        int n = base + w * 32 + g * 16 + q * 4 + r;
        if (n < nrows) {
          float v = acc[r] + bv[t];
          if (act) v = sspf(v);
          out[(long)n * 128 + f] = v;
        }
      }
    }
  }
}

// Edge kernel: per 128-edge tile, bf16 MFMA 2-layer MLP, cutoff scale,
// gather h[src], atomic scatter-add into agg[dst].
__global__ __launch_bounds__(256) void k_edge(
    const float* __restrict__ attr,   // [E][50]
    const int*   __restrict__ ei,     // [2][E]
    const float* __restrict__ ew,     // [E]
    const float* __restrict__ w1,     // [128][50]
    const float* __restrict__ b1,     // [128]
    const float* __restrict__ w2,     // [128][128]
    const float* __restrict__ b2,     // [128]
    const float* __restrict__ h,      // [NN][128]
    float*       __restrict__ agg)    // [NN][128]
{
  __shared__ __attribute__((aligned(16))) unsigned short s_he[128 * 128]; // 32 KB
  __shared__ __attribute__((aligned(16))) unsigned short s_w1[128 * 64];  // 16 KB
  __shared__ __attribute__((aligned(16))) unsigned short s_w2[128 * 128]; // 32 KB

  const int tid  = threadIdx.x;
  const int w    = tid >> 6;
  const int lane = tid & 63;
  const int q    = lane >> 4;
  const int n16  = lane & 15;

  // stage weights once (bf16, XOR-chunk swizzle, K zero-padded 50->64)
  for (int i = tid; i < 128 * 64; i += 256) {
    int f = i >> 6, k = i & 63;
    float v = (k < NG) ? w1[f * NG + k] : 0.f;
    int pos = (f << 6) + ((((k >> 3) ^ (f & 7)) << 3)) + (k & 7);
    s_w1[pos] = f2b(v);
  }
  for (int i = tid; i < 128 * 128; i += 256) {
    int f = i >> 7, k = i & 127;
    int pos = (f << 7) + ((((k >> 3) ^ (f & 15)) << 3)) + (k & 7);
    s_w2[pos] = f2b(w2[i]);
  }
  float b1v[8], b2v[8];
#pragma unroll
  for (int t = 0; t < 8; ++t) {
    b1v[t] = b1[t * 16 + n16];
    b2v[t] = b2[t * 16 + n16];
  }

  for (int tile = blockIdx.x; tile < N_TILES; tile += gridDim.x) {
    const int e0 = tile * TILE_E;
    __syncthreads();  // prior tile done with s_he region
    // stage attr tile (128 x 64, bf16, zero-pad, swizzled) into s_he[0:16KB]
    for (int i = tid; i < 128 * 64; i += 256) {
      int e = i >> 6, k = i & 63;
      float v = (k < NG) ? attr[(long)(e0 + e) * NG + k] : 0.f;
      int pos = (e << 6) + ((((k >> 3) ^ (e & 7)) << 3)) + (k & 7);
      s_he[pos] = f2b(v);
    }
    __syncthreads();
    // preload layer-1 A fragments (2 row-groups of 16 per wave)
    bf16x8 a1f[2][2];
#pragma unroll
    for (int g = 0; g < 2; ++g) {
      int er = w * 32 + g * 16 + n16;
      a1f[g][0] = *(const bf16x8*)&s_he[(er << 6) + (((q    ) ^ (er & 7)) << 3)];
      a1f[g][1] = *(const bf16x8*)&s_he[(er << 6) + (((4 + q) ^ (er & 7)) << 3)];
    }
    __syncthreads();  // attr in regs; region reusable as h_e

    // layer 1: h_e = ssp(attr @ w1^T + b1) -> LDS in A-layout
#pragma unroll
    for (int t = 0; t < 8; ++t) {
      int f = t * 16 + n16;
      bf16x8 bA = *(const bf16x8*)&s_w1[(f << 6) + (((q    ) ^ (f & 7)) << 3)];
      bf16x8 bB = *(const bf16x8*)&s_w1[(f << 6) + (((4 + q) ^ (f & 7)) << 3)];
      int kf = t * 16 + n16;
#pragma unroll
      for (int g = 0; g < 2; ++g) {
        f32x4 acc = {0.f, 0.f, 0.f, 0.f};
        acc = __builtin_amdgcn_mfma_f32_16x16x32_bf16(a1f[g][0], bA, acc, 0, 0, 0);
        acc = __builtin_amdgcn_mfma_f32_16x16x32_bf16(a1f[g][1], bB, acc, 0, 0, 0);
#pragma unroll
        for (int r = 0; r < 4; ++r) {
          int e = w * 32 + g * 16 + q * 4 + r;   // C-layout row
          float hv = sspf(acc[r] + b1v[t]);
          int pos = (e << 7) + ((((kf >> 3) ^ (e & 15)) << 3)) + (kf & 7);
          s_he[pos] = f2b(hv);
        }
      }
    }
    __syncthreads();

    // layer-2 A fragments
    bf16x8 a2f[2][4];
#pragma unroll
    for (int g = 0; g < 2; ++g) {
      int er = w * 32 + g * 16 + n16;
#pragma unroll
      for (int ks = 0; ks < 4; ++ks)
        a2f[g][ks] = *(const bf16x8*)&s_he[(er << 7) + (((ks * 4 + q) ^ (er & 15)) << 3)];
    }

    // per-edge epilogue metadata (8 edges/lane)
    int src[2][4], dst[2][4]; float cv[2][4];
#pragma unroll
    for (int g = 0; g < 2; ++g)
#pragma unroll
      for (int r = 0; r < 4; ++r) {
        int e = e0 + w * 32 + g * 16 + q * 4 + r;
        src[g][r] = ei[e];
        dst[g][r] = ei[E_NUM + e];
        // C = 0.5*(cos(ew*pi/10)+1); v_cos takes revolutions: ew*pi/10 / (2pi) = ew*0.05
        cv[g][r] = 0.5f * (__builtin_amdgcn_cosf(ew[e] * 0.05f) + 1.f);
      }

    // layer 2 + epilogue
#pragma unroll
    for (int t = 0; t < 8; ++t) {
      int f = t * 16 + n16;
      bf16x8 bb[4];
#pragma unroll
      for (int ks = 0; ks < 4; ++ks)
        bb[ks] = *(const bf16x8*)&s_w2[(f << 7) + (((ks * 4 + q) ^ (f & 15)) << 3)];
#pragma unroll
      for (int g = 0; g < 2; ++g) {
        f32x4 acc = {0.f, 0.f, 0.f, 0.f};
#pragma unroll
        for (int ks = 0; ks < 4; ++ks)
          acc = __builtin_amdgcn_mfma_f32_16x16x32_bf16(a2f[g][ks], bb[ks], acc, 0, 0, 0);
#pragma unroll
        for (int r = 0; r < 4; ++r) {
          float Wv = (acc[r] + b2v[t]) * cv[g][r];
          float msg = h[(long)src[g][r] * 128 + f] * Wv;
          atomicAdd(&agg[(long)dst[g][r] * 128 + f], msg);
        }
      }
    }
  }
}

extern "C" void kernel_launch(void* const* d_in, const int* in_sizes, int n_in,
                              void* d_out, int out_size, void* d_ws, size_t ws_size,
                              hipStream_t stream) {
  const float* x     = (const float*)d_in[0];
  const int*   ei    = (const int*)  d_in[1];
  const float* ew    = (const float*)d_in[2];
  const float* attr  = (const float*)d_in[3];
  const float* w1    = (const float*)d_in[4];
  const float* b1    = (const float*)d_in[5];
  const float* w2    = (const float*)d_in[6];
  const float* b2    = (const float*)d_in[7];
  const float* lin1w = (const float*)d_in[8];
  const float* lin2w = (const float*)d_in[9];
  const float* lin2b = (const float*)d_in[10];
  const float* linw  = (const float*)d_in[11];
  const float* linb  = (const float*)d_in[12];
  float* out = (float*)d_out;

  float* agg = (float*)d_ws;                       // [NN][128] fp32
  float* h   = agg + (size_t)NN * 128;             // [NN][128] fp32 (reused as h2)

  const int gemm_grid = (NN + 127) / 128;
  (void)hipMemsetAsync(agg, 0, (size_t)NN * 128 * sizeof(float), stream);
  k_mfma_gemm<<<gemm_grid, 256, 0, stream>>>(x, lin1w, nullptr, h, 0, NN);
  k_edge<<<EDGE_GRID, 256, 0, stream>>>(attr, ei, ew, w1, b1, w2, b2, h, agg);
  k_mfma_gemm<<<gemm_grid, 256, 0, stream>>>(agg, lin2w, lin2b, h, 1, NN);
  k_mfma_gemm<<<gemm_grid, 256, 0, stream>>>(h, linw, linb, out, 0, NN);
}